// Round 1
// baseline (579.247 us; speedup 1.0000x reference)
//
#include <hip/hip_runtime.h>
#include <cstdint>
#include <cstddef>

typedef __attribute__((ext_vector_type(4))) int i32x4;
typedef __bf16 bf16;
typedef __attribute__((ext_vector_type(8))) __bf16 bf16x8;
typedef __attribute__((ext_vector_type(4))) float f32x4;

#define BM 128
#define BN 128
#define BKB 128   // K-bytes per tile (i8): 128 i8 = 8 x 16B chunks per row
#define GROUP_M 16

__device__ __forceinline__ unsigned bf16_rne(float f) {
  unsigned u = __float_as_uint(f);
  unsigned r = 0x7FFFu + ((u >> 16) & 1u);
  return ((u + r) >> 16) & 0xFFFFu;
}
__device__ __forceinline__ unsigned pack2(float a, float b) {
  return bf16_rne(a) | (bf16_rne(b) << 16);
}
__device__ __forceinline__ int pack4i8(int a, int b, int c, int d) {
  return (a & 0xFF) | ((b & 0xFF) << 8) | ((c & 0xFF) << 16) | (d << 24);
}
__device__ __forceinline__ int q_i8(float v) {
  // clamp in float (v_med3-fusable), then round-to-nearest convert
  v = fminf(fmaxf(v, -127.0f), 127.0f);
  return __float2int_rn(v);
}

// ---------------- Phase 1 (merged): per-row int8 quantization ----------------
// blocks [0, M)      : quantize x row -> int8 + xscale[row]
// blocks [M, M+N)    : dequant W row (exact) -> row max -> int8 + wscale[row]
// One block per row, 256 threads. K must be 4096 (1024 16B chunks = 4 x 256).
//
// R3 change: fully lane-contiguous access. Thread t owns 16B chunks
// j = t + 256*i (i=0..3). Every load instruction is a contiguous 1KB/wave
// (vs the old lane-stride-64B pattern that scattered each instruction over
// 4KB and inflated the coalescer request rate ~8x). Stores are packed 4B
// ints at chunk index j (lane-contiguous). Chunk j covers elements
// [4j, 4j+4) -> group g = j>>5 (never straddles GROUP_SIZE=128).
__global__ __launch_bounds__(256) void prep_kernel(
    const float* __restrict__ x, char* __restrict__ xq, float* __restrict__ xscale,
    int M,
    const int* __restrict__ q, const float* __restrict__ scale,
    const int* __restrict__ zp, char* __restrict__ wq, float* __restrict__ wscale,
    int K, int G) {
  __shared__ float red[4];
  const int b = blockIdx.x;
  const int tid = threadIdx.x;
  float f[16];

  if (b < M) {
    const float4* src = (const float4*)(x + (size_t)b * K);
#pragma unroll
    for (int i = 0; i < 4; ++i) {
      float4 v = src[tid + 256 * i];
      f[4 * i + 0] = v.x; f[4 * i + 1] = v.y;
      f[4 * i + 2] = v.z; f[4 * i + 3] = v.w;
    }
  } else {
    const int row = b - M;
    const int4* src = (const int4*)(q + (size_t)row * K);
    const float* srow = scale + (size_t)row * G;
    const int*   zrow = zp + (size_t)row * G;
#pragma unroll
    for (int i = 0; i < 4; ++i) {
      const int j = tid + 256 * i;
      const int g = j >> 5;            // 32 chunks per 128-elem group
      const float s = srow[g];
      const float nzs = -s * (float)zrow[g];   // f = q*s - z*s
      int4 qv = src[j];
      f[4 * i + 0] = fmaf((float)qv.x, s, nzs);
      f[4 * i + 1] = fmaf((float)qv.y, s, nzs);
      f[4 * i + 2] = fmaf((float)qv.z, s, nzs);
      f[4 * i + 3] = fmaf((float)qv.w, s, nzs);
    }
  }

  float m = 0.f;
#pragma unroll
  for (int j = 0; j < 16; ++j) m = fmaxf(m, fabsf(f[j]));
#pragma unroll
  for (int off = 32; off >= 1; off >>= 1) m = fmaxf(m, __shfl_xor(m, off));
  if ((tid & 63) == 0) red[tid >> 6] = m;
  __syncthreads();
  m = fmaxf(fmaxf(red[0], red[1]), fmaxf(red[2], red[3]));

  const float inv = m > 0.f ? 127.0f / m : 0.f;
  int pk[4];
#pragma unroll
  for (int i = 0; i < 4; ++i)
    pk[i] = pack4i8(q_i8(f[4 * i + 0] * inv), q_i8(f[4 * i + 1] * inv),
                    q_i8(f[4 * i + 2] * inv), q_i8(f[4 * i + 3] * inv));

  char* dst = (b < M) ? (xq + (size_t)b * K) : (wq + (size_t)(b - M) * K);
  int* dst_i32 = (int*)dst;
#pragma unroll
  for (int i = 0; i < 4; ++i) dst_i32[tid + 256 * i] = pk[i];

  if (tid == 0) {
    if (b < M) xscale[b] = m * (1.0f / 127.0f);
    else       wscale[b - M] = m * (1.0f / 127.0f);
  }
}

// ---------------- Phase 2: i8 GEMM (m97 structure, BK=128 bytes) -------------
typedef __attribute__((address_space(1))) void gas_void;
typedef __attribute__((address_space(3))) void las_void;

__device__ __forceinline__ void load_lds16(const void* g, void* l) {
  __builtin_amdgcn_global_load_lds((gas_void*)g, (las_void*)l, 16, 0, 0);
}

// LDS layout identical to R1/R2 bf16 kernel (verified 0 bank conflicts):
// 16B chunk (row r, kq in [0,8)) at slot r*8 + (kq ^ (r&7)).
// Fragment read (i8 16x16x64): lane holds A[m=lane&15][k = quad*16 + j],
// j in [0,16) -> one ds_read_b128 of chunk kq = ks*4 + quad.
__global__ __launch_bounds__(256) void gemm_i8_kernel(
    const char* __restrict__ A,     // [M][K] i8
    const char* __restrict__ Bw,    // [N][K] i8
    const float* __restrict__ ascale,  // [M]
    const float* __restrict__ bscale,  // [N]
    const float* __restrict__ bias,    // [N]
    float* __restrict__ C,             // [M][N] fp32
    int M, int N, int K) {
  __shared__ __align__(16) char Alds[BM * BKB];
  __shared__ __align__(16) char Blds[BN * BKB];
  const int tid  = threadIdx.x;
  const int wave = tid >> 6;
  const int lane = tid & 63;
  const int quad = lane >> 4;
  const int l16  = lane & 15;

  // Grouped-m swizzle (R2: FETCH 1.46->0.79 GB, near per-XCD volume-optimal).
  const int nbm = M / BM;
  const int nbn = N / BN;
  int flat = blockIdx.x;
  int per_group = GROUP_M * nbn;
  int gid = flat / per_group;
  int rem = flat - gid * per_group;
  int gm = nbm - gid * GROUP_M;
  if (gm > GROUP_M) gm = GROUP_M;
  const int bm = (gid * GROUP_M + (rem % gm)) * BM;
  const int bn = (rem / gm) * BN;

  const int wm = (wave & 1) * 64;
  const int wn = (wave >> 1) * 64;

  i32x4 acc[4][4];
#pragma unroll
  for (int i = 0; i < 4; ++i)
#pragma unroll
    for (int j = 0; j < 4; ++j)
      acc[i][j] = (i32x4){0, 0, 0, 0};

  for (int kt = 0; kt < K; kt += BKB) {
#pragma unroll
    for (int t = 0; t < 4; ++t) {
      int s0 = (wave * 4 + t) * 64;   // wave-uniform LDS slot base
      int s  = s0 + lane;
      int m  = s >> 3;
      int kq = (s & 7) ^ (m & 7);
      load_lds16(A  + (size_t)(bm + m) * K + kt + kq * 16, &Alds[s0 * 16]);
      load_lds16(Bw + (size_t)(bn + m) * K + kt + kq * 16, &Blds[s0 * 16]);
    }
    __syncthreads();

#pragma unroll
    for (int ks = 0; ks < 2; ++ks) {
      i32x4 af[4], bfr[4];
#pragma unroll
      for (int tm = 0; tm < 4; ++tm) {
        int m  = wm + tm * 16 + l16;
        int kq = ks * 4 + quad;
        af[tm] = *(const i32x4*)&Alds[(m * 8 + (kq ^ (m & 7))) * 16];
      }
#pragma unroll
      for (int tn = 0; tn < 4; ++tn) {
        int n  = wn + tn * 16 + l16;
        int kq = ks * 4 + quad;
        bfr[tn] = *(const i32x4*)&Blds[(n * 8 + (kq ^ (n & 7))) * 16];
      }
#pragma unroll
      for (int tm = 0; tm < 4; ++tm)
#pragma unroll
        for (int tn = 0; tn < 4; ++tn)
          acc[tm][tn] = __builtin_amdgcn_mfma_i32_16x16x64_i8(
              af[tm], bfr[tn], acc[tm][tn], 0, 0, 0);
    }
    __syncthreads();
  }

  // Epilogue: D row = quad*4 + v, col = lane&15 (shape-determined, m121-128).
  // C = ascale[m] * bscale[n] * idot + bias[n]; nontemporal (write-once C).
#pragma unroll
  for (int tn = 0; tn < 4; ++tn) {
    int col = bn + wn + tn * 16 + l16;
    float bv = bias[col];
    float ws = bscale[col];
#pragma unroll
    for (int tm = 0; tm < 4; ++tm) {
      int row0 = bm + wm + tm * 16 + quad * 4;
#pragma unroll
      for (int v = 0; v < 4; ++v) {
        float val = ascale[row0 + v] * ws * (float)acc[tm][tn][v] + bv;
        __builtin_nontemporal_store(val, &C[(size_t)(row0 + v) * N + col]);
      }
    }
  }
}

// ---------------- Fallback: fused bf16 dequant GEMM (known-correct, R1) ------
__global__ __launch_bounds__(256) void gemm_fused_kernel(
    const float* __restrict__ X, const int* __restrict__ Q,
    const float* __restrict__ scale, const int* __restrict__ zp,
    const float* __restrict__ bias, float* __restrict__ C,
    int M, int N, int K, int G) {
  __shared__ __align__(16) bf16 Alds[128 * 64];
  __shared__ __align__(16) bf16 Blds[128 * 64];
  const int tid  = threadIdx.x;
  const int wave = tid >> 6;
  const int lane = tid & 63;
  const int quad = lane >> 4;
  const int l16  = lane & 15;
  const int bm = blockIdx.y * 128;
  const int bn = blockIdx.x * 128;
  const int wm = (wave & 1) * 64;
  const int wn = (wave >> 1) * 64;

  f32x4 acc[4][4];
#pragma unroll
  for (int i = 0; i < 4; ++i)
#pragma unroll
    for (int j = 0; j < 4; ++j)
      acc[i][j] = (f32x4){0.f, 0.f, 0.f, 0.f};

  for (int kt = 0; kt < K; kt += 64) {
#pragma unroll
    for (int i = 0; i < 4; ++i) {
      int c = tid + i * 256;
      int m = c >> 3;
      int kq = (c & 7) ^ (m & 7);
      const float* src = X + (size_t)(bm + m) * K + kt + kq * 8;
      float4 v0 = *(const float4*)src;
      float4 v1 = *(const float4*)(src + 4);
      uint4 p;
      p.x = pack2(v0.x, v0.y); p.y = pack2(v0.z, v0.w);
      p.z = pack2(v1.x, v1.y); p.w = pack2(v1.z, v1.w);
      *(uint4*)&Alds[c * 8] = p;
    }
#pragma unroll
    for (int i = 0; i < 4; ++i) {
      int c = tid + i * 256;
      int n = c >> 3;
      int kq = (c & 7) ^ (n & 7);
      int kcol = kt + kq * 8;
      size_t row = (size_t)(bn + n);
      int g = kcol >> 7;
      float s = scale[row * G + g];
      float z = (float)zp[row * G + g];
      const int* src = Q + row * K + kcol;
      int4 q0 = *(const int4*)src;
      int4 q1 = *(const int4*)(src + 4);
      uint4 p;
      p.x = pack2(((float)q0.x - z) * s, ((float)q0.y - z) * s);
      p.y = pack2(((float)q0.z - z) * s, ((float)q0.w - z) * s);
      p.z = pack2(((float)q1.x - z) * s, ((float)q1.y - z) * s);
      p.w = pack2(((float)q1.z - z) * s, ((float)q1.w - z) * s);
      *(uint4*)&Blds[c * 8] = p;
    }
    __syncthreads();

#pragma unroll
    for (int ks = 0; ks < 2; ++ks) {
      bf16x8 af[4], bfr[4];
#pragma unroll
      for (int tm = 0; tm < 4; ++tm) {
        int m  = wm + tm * 16 + l16;
        int kq = ks * 4 + quad;
        af[tm] = *(const bf16x8*)&Alds[(m * 8 + (kq ^ (m & 7))) * 8];
      }
#pragma unroll
      for (int tn = 0; tn < 4; ++tn) {
        int n  = wn + tn * 16 + l16;
        int kq = ks * 4 + quad;
        bfr[tn] = *(const bf16x8*)&Blds[(n * 8 + (kq ^ (n & 7))) * 8];
      }
#pragma unroll
      for (int tm = 0; tm < 4; ++tm)
#pragma unroll
        for (int tn = 0; tn < 4; ++tn)
          acc[tm][tn] = __builtin_amdgcn_mfma_f32_16x16x32_bf16(
              af[tm], bfr[tn], acc[tm][tn], 0, 0, 0);
    }
    __syncthreads();
  }

#pragma unroll
  for (int tn = 0; tn < 4; ++tn) {
    int col = bn + wn + tn * 16 + l16;
    float bv = bias[col];
#pragma unroll
    for (int tm = 0; tm < 4; ++tm) {
      int row0 = bm + wm + tm * 16 + quad * 4;
#pragma unroll
      for (int v = 0; v < 4; ++v)
        C[(size_t)(row0 + v) * N + col] = acc[tm][tn][v] + bv;
    }
  }
}

extern "C" void kernel_launch(void* const* d_in, const int* in_sizes, int n_in,
                              void* d_out, int out_size, void* d_ws, size_t ws_size,
                              hipStream_t stream) {
  const float* x     = (const float*)d_in[0];
  const int*   qw    = (const int*)d_in[1];
  const float* scale = (const float*)d_in[2];
  const int*   zp    = (const int*)d_in[3];
  const float* bias  = (const float*)d_in[4];
  float* out = (float*)d_out;

  const int O = in_sizes[4];                 // 11008
  const int I = (int)(in_sizes[1] / O);      // 4096
  const int M = (int)(in_sizes[0] / I);      // 4096 (= B*S)
  const int G = in_sizes[2] / O;             // 32
  const int K = I, N = O;

  // ws layout: xq[M*K] i8 | xscale[M] f32 | wq[N*K] i8 | wscale[N] f32
  size_t off_xq = 0;
  size_t off_xs = off_xq + (size_t)M * K;
  size_t off_wq = (off_xs + (size_t)M * 4 + 255) & ~(size_t)255;
  size_t off_ws_ = off_wq + (size_t)N * K;
  size_t need   = ((off_ws_ + (size_t)N * 4 + 255) & ~(size_t)255);

  if (ws_size >= need && K == 4096) {
    char*  xq = (char*)d_ws + off_xq;
    float* xs = (float*)((char*)d_ws + off_xs);
    char*  wq = (char*)d_ws + off_wq;
    float* wsc = (float*)((char*)d_ws + off_ws_);

    prep_kernel<<<M + N, 256, 0, stream>>>(x, xq, xs, M, qw, scale, zp, wq, wsc, K, G);

    int nblocks = (M / BM) * (N / BN);
    gemm_i8_kernel<<<nblocks, 256, 0, stream>>>(xq, wq, xs, wsc, bias, out, M, N, K);
  } else {
    dim3 gemm_grid((unsigned)(N / 128), (unsigned)(M / 128));
    gemm_fused_kernel<<<gemm_grid, 256, 0, stream>>>(x, qw, scale, zp, bias, out,
                                                     M, N, K, G);
  }
}

// Round 3
// 557.509 us; speedup vs baseline: 1.0390x; 1.0390x over previous
//
#include <hip/hip_runtime.h>
#include <cstdint>
#include <cstddef>

typedef __attribute__((ext_vector_type(4))) int i32x4;
typedef __bf16 bf16;
typedef __attribute__((ext_vector_type(8))) __bf16 bf16x8;
typedef __attribute__((ext_vector_type(4))) float f32x4;

#define BM 128
#define BN 128
#define BKB 128   // K-bytes per tile (i8) for the 128^2 fallback gemm
#define GROUP_M 16
#define GM256 4   // grouped-m for the 256^2 8-phase gemm
#define NXCD 8

__device__ __forceinline__ unsigned bf16_rne(float f) {
  unsigned u = __float_as_uint(f);
  unsigned r = 0x7FFFu + ((u >> 16) & 1u);
  return ((u + r) >> 16) & 0xFFFFu;
}
__device__ __forceinline__ unsigned pack2(float a, float b) {
  return bf16_rne(a) | (bf16_rne(b) << 16);
}
__device__ __forceinline__ int pack4i8(int a, int b, int c, int d) {
  return (a & 0xFF) | ((b & 0xFF) << 8) | ((c & 0xFF) << 16) | (d << 24);
}
__device__ __forceinline__ int q_i8(float v) {
  v = fminf(fmaxf(v, -127.0f), 127.0f);
  return __float2int_rn(v);
}

// ---------------- Phase 1 (merged): per-row int8 quantization ----------------
__global__ __launch_bounds__(256) void prep_kernel(
    const float* __restrict__ x, char* __restrict__ xq, float* __restrict__ xscale,
    int M,
    const int* __restrict__ q, const float* __restrict__ scale,
    const int* __restrict__ zp, char* __restrict__ wq, float* __restrict__ wscale,
    int K, int G) {
  __shared__ float red[4];
  const int b = blockIdx.x;
  const int tid = threadIdx.x;
  float f[16];

  if (b < M) {
    const float4* src = (const float4*)(x + (size_t)b * K);
#pragma unroll
    for (int i = 0; i < 4; ++i) {
      float4 v = src[tid + 256 * i];
      f[4 * i + 0] = v.x; f[4 * i + 1] = v.y;
      f[4 * i + 2] = v.z; f[4 * i + 3] = v.w;
    }
  } else {
    const int row = b - M;
    const int4* src = (const int4*)(q + (size_t)row * K);
    const float* srow = scale + (size_t)row * G;
    const int*   zrow = zp + (size_t)row * G;
#pragma unroll
    for (int i = 0; i < 4; ++i) {
      const int j = tid + 256 * i;
      const int g = j >> 5;            // 32 chunks per 128-elem group
      const float s = srow[g];
      const float nzs = -s * (float)zrow[g];   // f = q*s - z*s
      int4 qv = src[j];
      f[4 * i + 0] = fmaf((float)qv.x, s, nzs);
      f[4 * i + 1] = fmaf((float)qv.y, s, nzs);
      f[4 * i + 2] = fmaf((float)qv.z, s, nzs);
      f[4 * i + 3] = fmaf((float)qv.w, s, nzs);
    }
  }

  float m = 0.f;
#pragma unroll
  for (int j = 0; j < 16; ++j) m = fmaxf(m, fabsf(f[j]));
#pragma unroll
  for (int off = 32; off >= 1; off >>= 1) m = fmaxf(m, __shfl_xor(m, off));
  if ((tid & 63) == 0) red[tid >> 6] = m;
  __syncthreads();
  m = fmaxf(fmaxf(red[0], red[1]), fmaxf(red[2], red[3]));

  const float inv = m > 0.f ? 127.0f / m : 0.f;
  int pk[4];
#pragma unroll
  for (int i = 0; i < 4; ++i)
    pk[i] = pack4i8(q_i8(f[4 * i + 0] * inv), q_i8(f[4 * i + 1] * inv),
                    q_i8(f[4 * i + 2] * inv), q_i8(f[4 * i + 3] * inv));

  char* dst = (b < M) ? (xq + (size_t)b * K) : (wq + (size_t)(b - M) * K);
  int* dst_i32 = (int*)dst;
#pragma unroll
  for (int i = 0; i < 4; ++i) dst_i32[tid + 256 * i] = pk[i];

  if (tid == 0) {
    if (b < M) xscale[b] = m * (1.0f / 127.0f);
    else       wscale[b - M] = m * (1.0f / 127.0f);
  }
}

// ---------------- async global->LDS helper ----------------
typedef __attribute__((address_space(1))) void gas_void;
typedef __attribute__((address_space(3))) void las_void;

__device__ __forceinline__ void load_lds16(const void* g, void* l) {
  __builtin_amdgcn_global_load_lds((gas_void*)g, (las_void*)l, 16, 0, 0);
}

// ================== Phase 2 (R3): 256^2 4-phase i8 GEMM ======================
// R2 post-mortem: with the 2Mx4N wave grid, EVERY LDS half is read in EVERY
// phase by some wave (wmb=0 waves read A-half0 in all 4 quadrant phases, etc).
// R2 staged tile t+2 into buffer `cur` at ph3/ph4 -> the load data landed
// during ph4's ds_reads of the same half -> corruption (absmax 43).
//
// R3 schedule — PROVABLY race-free (no latency assumptions):
//   * stage ONLY tile t+1, ONLY into buffer `nxt` (never touch `cur`):
//       ph1: (t+1)A0+A1, ph2: (t+1)B0+B1  (front-loaded for drain slack)
//   * single vmcnt(0) + barrier at end of ph4.
//   Safety: (a) stages into nxt are issued after the end-of-tile barrier of
//   tile t-1 (all reads of nxt done; an LDS write cannot land before issue);
//   (b) reads of tile t+1 start only after vmcnt(0)+barrier at end of tile t.
// Keeps the 8-phase skeleton's mid-phase barrier + lgkmcnt(0)+sched_barrier(0)
// + setprio(1) around MFMA clusters (T3-structure + T5).
// LDS swizzle: 16B chunk kq of row r at slot r*8 + (kq ^ (r&7)) (0-conflict,
// verified in the 128^2 kernel). Linear LDS dest + pre-swizzled global source.

#define STAGE_A(buf, half, ktb) do {                                          \
    load_lds16(A + abase + (size_t)(half) * 128 * K + (size_t)(ktb) + off0,   \
               &Al[buf][(half) * 16384 + d0w]);                               \
    load_lds16(A + abase + (size_t)(half) * 128 * K + (size_t)(ktb) + off1,   \
               &Al[buf][(half) * 16384 + d1w]);                               \
  } while (0)

#define STAGE_B(buf, half, ktb) do {                                          \
    load_lds16(Bw + bbase + (size_t)(half) * 128 * K + (size_t)(ktb) + off0,  \
               &Bl[buf][(half) * 16384 + d0w]);                               \
    load_lds16(Bw + bbase + (size_t)(half) * 128 * K + (size_t)(ktb) + off1,  \
               &Bl[buf][(half) * 16384 + d1w]);                               \
  } while (0)

#define PHASE(CUR, MH, NH, STAGE_STMT, WAIT_STMT) do {                        \
    i32x4 afr[4][2], bfr[2][2];                                               \
    _Pragma("unroll")                                                         \
    for (int tm = 0; tm < 4; ++tm) {                                          \
      _Pragma("unroll")                                                       \
      for (int ks = 0; ks < 2; ++ks) {                                        \
        int row = wmb + (MH) * 64 + tm * 16 + l16;                            \
        int kq  = ks * 4 + quad;                                              \
        afr[tm][ks] =                                                         \
            *(const i32x4*)&Al[CUR][(row * 8 + (kq ^ (row & 7))) * 16];       \
      }                                                                       \
    }                                                                         \
    _Pragma("unroll")                                                         \
    for (int tn = 0; tn < 2; ++tn) {                                          \
      _Pragma("unroll")                                                       \
      for (int ks = 0; ks < 2; ++ks) {                                        \
        int row = wnb + (NH) * 32 + tn * 16 + l16;                            \
        int kq  = ks * 4 + quad;                                              \
        bfr[tn][ks] =                                                         \
            *(const i32x4*)&Bl[CUR][(row * 8 + (kq ^ (row & 7))) * 16];       \
      }                                                                       \
    }                                                                         \
    STAGE_STMT;                                                               \
    __builtin_amdgcn_s_barrier();                                             \
    asm volatile("s_waitcnt lgkmcnt(0)" ::: "memory");                        \
    __builtin_amdgcn_sched_barrier(0);                                        \
    __builtin_amdgcn_s_setprio(1);                                            \
    _Pragma("unroll")                                                         \
    for (int tm = 0; tm < 4; ++tm) {                                          \
      _Pragma("unroll")                                                       \
      for (int tn = 0; tn < 2; ++tn) {                                        \
        _Pragma("unroll")                                                     \
        for (int ks = 0; ks < 2; ++ks) {                                      \
          acc[(MH) * 4 + tm][(NH) * 2 + tn] =                                 \
              __builtin_amdgcn_mfma_i32_16x16x64_i8(                          \
                  afr[tm][ks], bfr[tn][ks],                                   \
                  acc[(MH) * 4 + tm][(NH) * 2 + tn], 0, 0, 0);                \
        }                                                                     \
      }                                                                       \
    }                                                                         \
    __builtin_amdgcn_s_setprio(0);                                            \
    WAIT_STMT;                                                                \
    __builtin_amdgcn_s_barrier();                                             \
    __builtin_amdgcn_sched_barrier(0);                                        \
  } while (0)

__global__ __launch_bounds__(512) void gemm_i8_256(
    const char* __restrict__ A,        // [M][K] i8
    const char* __restrict__ Bw,       // [N][K] i8
    const float* __restrict__ ascale,  // [M]
    const float* __restrict__ bscale,  // [N]
    const float* __restrict__ bias,    // [N]
    float* __restrict__ C,             // [M][N] fp32
    int M, int N, int K) {
  __shared__ __align__(16) char Al[2][256 * 128];
  __shared__ __align__(16) char Bl[2][256 * 128];
  const int tid  = threadIdx.x;
  const int wave = tid >> 6;
  const int lane = tid & 63;
  const int quad = lane >> 4;
  const int l16  = lane & 15;
  const int wmb  = (wave >> 2) * 128;  // wave row base within tile (2 M-waves)
  const int wnb  = (wave & 3) * 64;    // wave col base within tile (4 N-waves)

  // XCD-bijective chunked remap (launcher guarantees nblocks % 8 == 0)
  const int nbm = M / 256, nbn = N / 256;
  const int cpx = (nbm * nbn) / NXCD;
  const int swz = ((int)blockIdx.x % NXCD) * cpx + (int)blockIdx.x / NXCD;
  // grouped-m
  const int per_group = GM256 * nbn;
  const int gid = swz / per_group;
  const int rem = swz - gid * per_group;
  int gm = nbm - gid * GM256; if (gm > GM256) gm = GM256;
  const int bm = (gid * GM256 + (rem % gm)) * 256;
  const int bn = (rem / gm) * 256;

  // staging per-thread invariants: thread t owns linear slots {tid, 512+tid}
  // of each 128-row half (1024 slots = 128 rows x 8 chunks).
  const int sA = tid, sB = 512 + tid;
  const int m0 = sA >> 3, m1 = sB >> 3;
  const size_t off0 = (size_t)m0 * K + (size_t)(((sA & 7) ^ (m0 & 7)) * 16);
  const size_t off1 = (size_t)m1 * K + (size_t)(((sB & 7) ^ (m1 & 7)) * 16);
  const int d0w = (0 * 512 + wave * 64) * 16;   // wave-uniform LDS dest bases
  const int d1w = (1 * 512 + wave * 64) * 16;
  const size_t abase = (size_t)bm * K;
  const size_t bbase = (size_t)bn * K;
  const int NT = K / 128;

  i32x4 acc[8][4];
#pragma unroll
  for (int i = 0; i < 8; ++i)
#pragma unroll
    for (int j = 0; j < 4; ++j)
      acc[i][j] = (i32x4){0, 0, 0, 0};

  // Prologue: stage tile0 fully (both buffers' reads haven't begun), drain.
  STAGE_A(0, 0, 0);
  STAGE_A(0, 1, 0);
  STAGE_B(0, 0, 0);
  STAGE_B(0, 1, 0);
  asm volatile("s_waitcnt vmcnt(0)" ::: "memory");
  __builtin_amdgcn_s_barrier();
  __builtin_amdgcn_sched_barrier(0);

  for (int t = 0; t < NT; ++t) {
    const int cur = t & 1;
    const int nxt = cur ^ 1;
    const int kt1 = (t + 1) * 128;
    const bool s1 = (t + 1) < NT;

    PHASE(cur, 0, 0, { if (s1) { STAGE_A(nxt, 0, kt1); STAGE_A(nxt, 1, kt1); } }, {});
    PHASE(cur, 1, 0, { if (s1) { STAGE_B(nxt, 0, kt1); STAGE_B(nxt, 1, kt1); } }, {});
    PHASE(cur, 0, 1, {}, {});
    PHASE(cur, 1, 1, {},
          { asm volatile("s_waitcnt vmcnt(0)" ::: "memory"); });
  }

  // Epilogue: D row = quad*4 + v, col = lane&15 (shape-determined).
  // acc[i][j] covers row offset 16*i, col offset 16*j of the wave's 128x64.
#pragma unroll
  for (int tn = 0; tn < 4; ++tn) {
    int col = bn + wnb + tn * 16 + l16;
    float bv = bias[col];
    float ws = bscale[col];
#pragma unroll
    for (int tm = 0; tm < 8; ++tm) {
      int row0 = bm + wmb + tm * 16 + quad * 4;
#pragma unroll
      for (int v = 0; v < 4; ++v) {
        float val = ascale[row0 + v] * ws * (float)acc[tm][tn][v] + bv;
        __builtin_nontemporal_store(val, &C[(size_t)(row0 + v) * N + col]);
      }
    }
  }
}

// ---------------- Fallback A: 128^2 i8 GEMM (known-good) ---------------------
__global__ __launch_bounds__(256) void gemm_i8_kernel(
    const char* __restrict__ A, const char* __restrict__ Bw,
    const float* __restrict__ ascale, const float* __restrict__ bscale,
    const float* __restrict__ bias, float* __restrict__ C,
    int M, int N, int K) {
  __shared__ __align__(16) char Alds[BM * BKB];
  __shared__ __align__(16) char Blds[BN * BKB];
  const int tid  = threadIdx.x;
  const int wave = tid >> 6;
  const int lane = tid & 63;
  const int quad = lane >> 4;
  const int l16  = lane & 15;

  const int nbm = M / BM;
  const int nbn = N / BN;
  int flat = blockIdx.x;
  int per_group = GROUP_M * nbn;
  int gid = flat / per_group;
  int rem = flat - gid * per_group;
  int gm = nbm - gid * GROUP_M;
  if (gm > GROUP_M) gm = GROUP_M;
  const int bm = (gid * GROUP_M + (rem % gm)) * BM;
  const int bn = (rem / gm) * BN;

  const int wm = (wave & 1) * 64;
  const int wn = (wave >> 1) * 64;

  i32x4 acc[4][4];
#pragma unroll
  for (int i = 0; i < 4; ++i)
#pragma unroll
    for (int j = 0; j < 4; ++j)
      acc[i][j] = (i32x4){0, 0, 0, 0};

  for (int kt = 0; kt < K; kt += BKB) {
#pragma unroll
    for (int t = 0; t < 4; ++t) {
      int s0 = (wave * 4 + t) * 64;
      int s  = s0 + lane;
      int m  = s >> 3;
      int kq = (s & 7) ^ (m & 7);
      load_lds16(A  + (size_t)(bm + m) * K + kt + kq * 16, &Alds[s0 * 16]);
      load_lds16(Bw + (size_t)(bn + m) * K + kt + kq * 16, &Blds[s0 * 16]);
    }
    __syncthreads();

#pragma unroll
    for (int ks = 0; ks < 2; ++ks) {
      i32x4 af[4], bfr[4];
#pragma unroll
      for (int tm = 0; tm < 4; ++tm) {
        int m  = wm + tm * 16 + l16;
        int kq = ks * 4 + quad;
        af[tm] = *(const i32x4*)&Alds[(m * 8 + (kq ^ (m & 7))) * 16];
      }
#pragma unroll
      for (int tn = 0; tn < 4; ++tn) {
        int n  = wn + tn * 16 + l16;
        int kq = ks * 4 + quad;
        bfr[tn] = *(const i32x4*)&Blds[(n * 8 + (kq ^ (n & 7))) * 16];
      }
#pragma unroll
      for (int tm = 0; tm < 4; ++tm)
#pragma unroll
        for (int tn = 0; tn < 4; ++tn)
          acc[tm][tn] = __builtin_amdgcn_mfma_i32_16x16x64_i8(
              af[tm], bfr[tn], acc[tm][tn], 0, 0, 0);
    }
    __syncthreads();
  }

#pragma unroll
  for (int tn = 0; tn < 4; ++tn) {
    int col = bn + wn + tn * 16 + l16;
    float bv = bias[col];
    float ws = bscale[col];
#pragma unroll
    for (int tm = 0; tm < 4; ++tm) {
      int row0 = bm + wm + tm * 16 + quad * 4;
#pragma unroll
      for (int v = 0; v < 4; ++v) {
        float val = ascale[row0 + v] * ws * (float)acc[tm][tn][v] + bv;
        __builtin_nontemporal_store(val, &C[(size_t)(row0 + v) * N + col]);
      }
    }
  }
}

// ---------------- Fallback B: fused bf16 dequant GEMM (known-correct) --------
__global__ __launch_bounds__(256) void gemm_fused_kernel(
    const float* __restrict__ X, const int* __restrict__ Q,
    const float* __restrict__ scale, const int* __restrict__ zp,
    const float* __restrict__ bias, float* __restrict__ C,
    int M, int N, int K, int G) {
  __shared__ __align__(16) bf16 Alds[128 * 64];
  __shared__ __align__(16) bf16 Blds[128 * 64];
  const int tid  = threadIdx.x;
  const int wave = tid >> 6;
  const int lane = tid & 63;
  const int quad = lane >> 4;
  const int l16  = lane & 15;
  const int bm = blockIdx.y * 128;
  const int bn = blockIdx.x * 128;
  const int wm = (wave & 1) * 64;
  const int wn = (wave >> 1) * 64;

  f32x4 acc[4][4];
#pragma unroll
  for (int i = 0; i < 4; ++i)
#pragma unroll
    for (int j = 0; j < 4; ++j)
      acc[i][j] = (f32x4){0.f, 0.f, 0.f, 0.f};

  for (int kt = 0; kt < K; kt += 64) {
#pragma unroll
    for (int i = 0; i < 4; ++i) {
      int c = tid + i * 256;
      int m = c >> 3;
      int kq = (c & 7) ^ (m & 7);
      const float* src = X + (size_t)(bm + m) * K + kt + kq * 8;
      float4 v0 = *(const float4*)src;
      float4 v1 = *(const float4*)(src + 4);
      uint4 p;
      p.x = pack2(v0.x, v0.y); p.y = pack2(v0.z, v0.w);
      p.z = pack2(v1.x, v1.y); p.w = pack2(v1.z, v1.w);
      *(uint4*)&Alds[c * 8] = p;
    }
#pragma unroll
    for (int i = 0; i < 4; ++i) {
      int c = tid + i * 256;
      int n = c >> 3;
      int kq = (c & 7) ^ (n & 7);
      int kcol = kt + kq * 8;
      size_t row = (size_t)(bn + n);
      int g = kcol >> 7;
      float s = scale[row * G + g];
      float z = (float)zp[row * G + g];
      const int* src = Q + row * K + kcol;
      int4 q0 = *(const int4*)src;
      int4 q1 = *(const int4*)(src + 4);
      uint4 p;
      p.x = pack2(((float)q0.x - z) * s, ((float)q0.y - z) * s);
      p.y = pack2(((float)q0.z - z) * s, ((float)q0.w - z) * s);
      p.z = pack2(((float)q1.x - z) * s, ((float)q1.y - z) * s);
      p.w = pack2(((float)q1.z - z) * s, ((float)q1.w - z) * s);
      *(uint4*)&Blds[c * 8] = p;
    }
    __syncthreads();

#pragma unroll
    for (int ks = 0; ks < 2; ++ks) {
      bf16x8 af[4], bfr[4];
#pragma unroll
      for (int tm = 0; tm < 4; ++tm) {
        int m  = wm + tm * 16 + l16;
        int kq = ks * 4 + quad;
        af[tm] = *(const bf16x8*)&Alds[(m * 8 + (kq ^ (m & 7))) * 8];
      }
#pragma unroll
      for (int tn = 0; tn < 4; ++tn) {
        int n  = wn + tn * 16 + l16;
        int kq = ks * 4 + quad;
        bfr[tn] = *(const bf16x8*)&Blds[(n * 8 + (kq ^ (n & 7))) * 8];
      }
#pragma unroll
      for (int tm = 0; tm < 4; ++tm)
#pragma unroll
        for (int tn = 0; tn < 4; ++tn)
          acc[tm][tn] = __builtin_amdgcn_mfma_f32_16x16x32_bf16(
              af[tm], bfr[tn], acc[tm][tn], 0, 0, 0);
    }
    __syncthreads();
  }

#pragma unroll
  for (int tn = 0; tn < 4; ++tn) {
    int col = bn + wn + tn * 16 + l16;
    float bv = bias[col];
#pragma unroll
    for (int tm = 0; tm < 4; ++tm) {
      int row0 = bm + wm + tm * 16 + quad * 4;
#pragma unroll
      for (int v = 0; v < 4; ++v)
        C[(size_t)(row0 + v) * N + col] = acc[tm][tn][v] + bv;
    }
  }
}

extern "C" void kernel_launch(void* const* d_in, const int* in_sizes, int n_in,
                              void* d_out, int out_size, void* d_ws, size_t ws_size,
                              hipStream_t stream) {
  const float* x     = (const float*)d_in[0];
  const int*   qw    = (const int*)d_in[1];
  const float* scale = (const float*)d_in[2];
  const int*   zp    = (const int*)d_in[3];
  const float* bias  = (const float*)d_in[4];
  float* out = (float*)d_out;

  const int O = in_sizes[4];                 // 11008
  const int I = (int)(in_sizes[1] / O);      // 4096
  const int M = (int)(in_sizes[0] / I);      // 4096 (= B*S)
  const int G = in_sizes[2] / O;             // 32
  const int K = I, N = O;

  // ws layout: xq[M*K] i8 | xscale[M] f32 | wq[N*K] i8 | wscale[N] f32
  size_t off_xq = 0;
  size_t off_xs = off_xq + (size_t)M * K;
  size_t off_wq = (off_xs + (size_t)M * 4 + 255) & ~(size_t)255;
  size_t off_ws_ = off_wq + (size_t)N * K;
  size_t need   = ((off_ws_ + (size_t)N * 4 + 255) & ~(size_t)255);

  if (ws_size >= need && K == 4096) {
    char*  xq = (char*)d_ws + off_xq;
    float* xs = (float*)((char*)d_ws + off_xs);
    char*  wq = (char*)d_ws + off_wq;
    float* wsc = (float*)((char*)d_ws + off_ws_);

    prep_kernel<<<M + N, 256, 0, stream>>>(x, xq, xs, M, qw, scale, zp, wq, wsc, K, G);

    const int nb256 = (M / 256) * (N / 256);
    if ((M % 256) == 0 && (N % 256) == 0 && (nb256 % NXCD) == 0) {
      gemm_i8_256<<<nb256, 512, 0, stream>>>(xq, wq, xs, wsc, bias, out, M, N, K);
    } else {
      int nblocks = (M / BM) * (N / BN);
      gemm_i8_kernel<<<nblocks, 256, 0, stream>>>(xq, wq, xs, wsc, bias, out, M, N, K);
    }
  } else {
    dim3 gemm_grid((unsigned)(N / 128), (unsigned)(M / 128));
    gemm_fused_kernel<<<gemm_grid, 256, 0, stream>>>(x, qw, scale, zp, bias, out,
                                                     M, N, K, G);
  }
}